// Round 5
// baseline (822.533 us; speedup 1.0000x reference)
//
#include <hip/hip_runtime.h>
#include <hip/hip_bf16.h>

#define IN_DIM 512
#define OUT_DIM 128

// Bt swizzle: row stride 144 words; word c stored at c + 4*(c>>5).
// Bijective within a row; read bank-starts become 2-way max (free per m136).
#define BIDX(k, c) ((k)*144 + (c) + (((c) >> 5) << 2))

// ---------------------------------------------------------------------------
// Dual GEMM: one dispatch computes both encoders (packs the per-GEMM tail
// rounds together; same-stream kernels would serialize).
//   blocks [0, nb0)      : C0[M0][128] = A0[M0][512] @ W0 + b0
//   blocks [nb0, nb0+nb1): C1[M1][128] = A1[M1][512] @ W1 + b1
// block = 256 threads, tile 128 rows x 128 cols, per-thread 8x8 micro-tile.
// fp32 vector FMA (no fp32-input MFMA on CDNA4).
// ---------------------------------------------------------------------------
__global__ __launch_bounds__(256) void gemm_dual_kernel(
    const float* __restrict__ A0, const float* __restrict__ W0,
    const float* __restrict__ b0, float* __restrict__ C0, int M0, int nb0,
    const float* __restrict__ A1, const float* __restrict__ W1,
    const float* __restrict__ b1, float* __restrict__ C1, int M1)
{
    __shared__ float At[16][128];     // A tile transposed: At[k][r]
    __shared__ float BtF[16 * 144];   // W tile, swizzled: word c at BIDX(k,c)

    // Block-uniform problem select (no lane divergence).
    const float* A; const float* W; const float* bias; float* C; int M, bid;
    if ((int)blockIdx.x < nb0) {
        A = A0; W = W0; bias = b0; C = C0; M = M0; bid = blockIdx.x;
    } else {
        A = A1; W = W1; bias = b1; C = C1; M = M1; bid = blockIdx.x - nb0;
    }

    const int tid  = threadIdx.x;
    const int row0 = bid * 128;
    const int rg = tid >> 4;        // 0..15
    const int cg = tid & 15;        // 0..15
    const int r0 = rg * 8;
    const int c0 = cg * 8;

    float acc[8][8];
#pragma unroll
    for (int i = 0; i < 8; ++i)
#pragma unroll
        for (int j = 0; j < 8; ++j) acc[i][j] = 0.0f;

    // A staging map: thread t loads row (t>>1), k-offset (t&1)*8, 8 floats
    const int ra = tid >> 1;
    const int ka = (tid & 1) * 8;
    int arow = row0 + ra;
    if (arow > M - 1) arow = M - 1;           // clamp OOB reads, stores guarded
    const float* aptr = A + (size_t)arow * IN_DIM + ka;

    // B staging map: thread t loads k=(t>>4), cols (t&15)*8 .. +7
    const int kb = tid >> 4;
    const int cb = (tid & 15) * 8;
    const float* wptr = W + (size_t)kb * OUT_DIM + cb;

    for (int kk = 0; kk < IN_DIM; kk += 16) {
        const float4 a0 = *(const float4*)(aptr + kk);
        const float4 a1 = *(const float4*)(aptr + kk + 4);
        const float4 b0v = *(const float4*)(wptr + (size_t)kk * OUT_DIM);
        const float4 b1v = *(const float4*)(wptr + (size_t)kk * OUT_DIM + 4);
        __syncthreads();
        At[ka + 0][ra] = a0.x; At[ka + 1][ra] = a0.y;
        At[ka + 2][ra] = a0.z; At[ka + 3][ra] = a0.w;
        At[ka + 4][ra] = a1.x; At[ka + 5][ra] = a1.y;
        At[ka + 6][ra] = a1.z; At[ka + 7][ra] = a1.w;
        // cb % 32 in {0,8,16,24} -> cb..cb+7 share one 32-word block:
        // one swizzle shift applies to both float4s.
        *(float4*)&BtF[BIDX(kb, cb)]     = b0v;
        *(float4*)&BtF[BIDX(kb, cb) + 4] = b1v;
        __syncthreads();
#pragma unroll
        for (int k = 0; k < 16; ++k) {
            const float4 av0 = *(const float4*)&At[k][r0];
            const float4 av1 = *(const float4*)&At[k][r0 + 4];
            const float4 bv0 = *(const float4*)&BtF[BIDX(k, c0)];
            const float4 bv1 = *(const float4*)&BtF[BIDX(k, c0) + 4];
            const float ar[8] = {av0.x, av0.y, av0.z, av0.w,
                                 av1.x, av1.y, av1.z, av1.w};
            const float bc[8] = {bv0.x, bv0.y, bv0.z, bv0.w,
                                 bv1.x, bv1.y, bv1.z, bv1.w};
#pragma unroll
            for (int i = 0; i < 8; ++i)
#pragma unroll
                for (int j = 0; j < 8; ++j)
                    acc[i][j] = fmaf(ar[i], bc[j], acc[i][j]);
        }
    }

    const float4 bb0 = *(const float4*)(bias + c0);
    const float4 bb1 = *(const float4*)(bias + c0 + 4);
#pragma unroll
    for (int i = 0; i < 8; ++i) {
        const int r = row0 + r0 + i;
        if (r < M) {
            float4 o0 = make_float4(acc[i][0] + bb0.x, acc[i][1] + bb0.y,
                                    acc[i][2] + bb0.z, acc[i][3] + bb0.w);
            float4 o1 = make_float4(acc[i][4] + bb1.x, acc[i][5] + bb1.y,
                                    acc[i][6] + bb1.z, acc[i][7] + bb1.w);
            *(float4*)(C + (size_t)r * OUT_DIM + c0)     = o0;
            *(float4*)(C + (size_t)r * OUT_DIM + c0 + 4) = o1;
        }
    }
}

// ---------------------------------------------------------------------------
// In-degree count over target nodes (self-loop added analytically later)
// ---------------------------------------------------------------------------
__global__ void count_kernel(const int* __restrict__ col, int* __restrict__ cnt,
                             int E)
{
    for (int e = blockIdx.x * blockDim.x + threadIdx.x; e < E;
         e += gridDim.x * blockDim.x)
        atomicAdd(&cnt[col[e]], 1);
}

__global__ void dinv_kernel(const int* __restrict__ cnt,
                            float* __restrict__ dinv, int N)
{
    int n = blockIdx.x * blockDim.x + threadIdx.x;
    if (n < N) dinv[n] = rsqrtf((float)cnt[n] + 1.0f);  // deg = cnt + self loop
}

// ---------------------------------------------------------------------------
// Thread-coarsened single-block exclusive scan: each of 1024 threads serially
// reduces a contiguous slice, one 10-step shared scan of totals, serial
// write-back. ~20 barriers total.
// ---------------------------------------------------------------------------
__global__ __launch_bounds__(1024) void scan_kernel(
    const int* __restrict__ cnt, int* __restrict__ off, int* __restrict__ cur,
    int N)
{
    __shared__ int buf[1024];
    const int tid   = threadIdx.x;
    const int chunk = (N + 1023) / 1024;
    const int lo    = tid * chunk;
    const int hi    = min(N, lo + chunk);

    int total = 0;
    for (int i = lo; i < hi; ++i) total += cnt[i];
    buf[tid] = total;
    __syncthreads();
#pragma unroll
    for (int ofs = 1; ofs < 1024; ofs <<= 1) {
        const int t = (tid >= ofs) ? buf[tid - ofs] : 0;
        __syncthreads();
        buf[tid] += t;
        __syncthreads();
    }
    int running = buf[tid] - total;   // exclusive prefix of this slice
    for (int i = lo; i < hi; ++i) {
        off[i] = running;
        cur[i] = running;
        running += cnt[i];
    }
    if (tid == 1023) off[N] = running;
}

// ---------------------------------------------------------------------------
// CSR fill: bucket edges by target; store source index + dinv[source]
// ---------------------------------------------------------------------------
__global__ void fill_kernel(const int* __restrict__ row,
                            const int* __restrict__ col,
                            const float* __restrict__ dinv,
                            int* __restrict__ cur, int* __restrict__ csr_row,
                            float* __restrict__ csr_w, int E)
{
    for (int e = blockIdx.x * blockDim.x + threadIdx.x; e < E;
         e += gridDim.x * blockDim.x) {
        const int c = col[e];
        const int r = row[e];
        const int p = atomicAdd(&cur[c], 1);
        csr_row[p] = r;
        csr_w[p]   = dinv[r];
    }
}

// ---------------------------------------------------------------------------
// Gather-form SpMM + APPNP update:
//   hout[n] = 0.9*( dinv[n]*sum_e w_e*hin[src_e] + dinv[n]^2*hin[n] ) + 0.1*h0[n]
// One wave per node; lane handles features (2*lane, 2*lane+1).
// ---------------------------------------------------------------------------
__global__ __launch_bounds__(256) void spmm_kernel(
    const float* __restrict__ hin, const float* __restrict__ h0,
    const float* __restrict__ dinv, const int* __restrict__ off,
    const int* __restrict__ csr_row, const float* __restrict__ csr_w,
    float* __restrict__ hout, int N)
{
    const int wave = threadIdx.x >> 6;
    const int lane = threadIdx.x & 63;
    const int n = blockIdx.x * 4 + wave;
    if (n >= N) return;
    const int f = lane * 2;

    float acc0 = 0.0f, acc1 = 0.0f;
    const int s = off[n];
    const int e = off[n + 1];

    int i = s;
    for (; i + 3 < e; i += 4) {      // 4-way unroll for load ILP
        const int   r0i = csr_row[i],     r1i = csr_row[i + 1];
        const int   r2i = csr_row[i + 2], r3i = csr_row[i + 3];
        const float w0 = csr_w[i],     w1 = csr_w[i + 1];
        const float w2 = csr_w[i + 2], w3 = csr_w[i + 3];
        const float2 v0 = *(const float2*)(hin + (size_t)r0i * OUT_DIM + f);
        const float2 v1 = *(const float2*)(hin + (size_t)r1i * OUT_DIM + f);
        const float2 v2 = *(const float2*)(hin + (size_t)r2i * OUT_DIM + f);
        const float2 v3 = *(const float2*)(hin + (size_t)r3i * OUT_DIM + f);
        acc0 = fmaf(w0, v0.x, fmaf(w1, v1.x, fmaf(w2, v2.x, fmaf(w3, v3.x, acc0))));
        acc1 = fmaf(w0, v0.y, fmaf(w1, v1.y, fmaf(w2, v2.y, fmaf(w3, v3.y, acc1))));
    }
    for (; i < e; ++i) {
        const int   r = csr_row[i];
        const float w = csr_w[i];
        const float2 v = *(const float2*)(hin + (size_t)r * OUT_DIM + f);
        acc0 = fmaf(w, v.x, acc0);
        acc1 = fmaf(w, v.y, acc1);
    }

    const float di  = dinv[n];
    const float2 hs  = *(const float2*)(hin + (size_t)n * OUT_DIM + f);
    const float2 h0v = *(const float2*)(h0  + (size_t)n * OUT_DIM + f);
    float2 o;
    o.x = 0.9f * (di * acc0 + di * di * hs.x) + 0.1f * h0v.x;
    o.y = 0.9f * (di * acc1 + di * di * hs.y) + 0.1f * h0v.y;
    *(float2*)(hout + (size_t)n * OUT_DIM + f) = o;
}

// ---------------------------------------------------------------------------
extern "C" void kernel_launch(void* const* d_in, const int* in_sizes, int n_in,
                              void* d_out, int out_size, void* d_ws,
                              size_t ws_size, hipStream_t stream)
{
    const float* x     = (const float*)d_in[0];
    const int*   ei    = (const int*)d_in[1];
    const float* q_emb = (const float*)d_in[2];
    const float* W_t   = (const float*)d_in[3];
    const float* b_t   = (const float*)d_in[4];
    const float* W_q   = (const float*)d_in[5];
    const float* b_q   = (const float*)d_in[6];

    const int OUT = in_sizes[4];            // 128
    const int IN  = in_sizes[3] / OUT;      // 512
    const int N   = in_sizes[0] / IN;       // 50000
    const int E   = in_sizes[1] / 2;        // 800000
    const int NQ  = in_sizes[2] / IN;       // 100000

    const int* row = ei;                    // edge_index[0] (source)
    const int* col = ei + E;                // edge_index[1] (target)

    // Workspace layout (256B-aligned slices)
    char*  w   = (char*)d_ws;
    size_t ofs = 0;
    auto take = [&](size_t bytes) -> void* {
        void* p = w + ofs;
        ofs += (bytes + 255) & ~(size_t)255;
        return p;
    };
    float* h0    = (float*)take((size_t)N * OUT * 4);
    float* h1    = (float*)take((size_t)N * OUT * 4);
    float* dinv  = (float*)take((size_t)N * 4);
    int*   cnt   = (int*)take((size_t)N * 4);
    int*   offp  = (int*)take((size_t)(N + 1) * 4);
    int*   cur   = (int*)take((size_t)N * 4);
    int*   csr_r = (int*)take((size_t)E * 4);
    float* csr_w = (float*)take((size_t)E * 4);
    (void)ws_size; (void)n_in; (void)out_size;

    float* out_q = (float*)d_out;                       // [NQ, OUT]
    float* out_h = (float*)d_out + (size_t)NQ * OUT;    // [N, OUT]

    hipMemsetAsync(cnt, 0, (size_t)N * 4, stream);

    // Dense encoders — single fused dispatch (packs tail rounds together)
    const int nb_q = (NQ + 127) / 128;      // 782
    const int nb_t = (N + 127) / 128;       // 391
    gemm_dual_kernel<<<nb_q + nb_t, 256, 0, stream>>>(
        q_emb, W_q, b_q, out_q, NQ, nb_q,
        x,     W_t, b_t, h0,    N);

    // Graph preprocessing: degree -> dinv -> CSR by target
    count_kernel<<<1024, 256, 0, stream>>>(col, cnt, E);
    dinv_kernel<<<(N + 255) / 256, 256, 0, stream>>>(cnt, dinv, N);
    scan_kernel<<<1, 1024, 0, stream>>>(cnt, offp, cur, N);
    fill_kernel<<<1024, 256, 0, stream>>>(row, col, dinv, cur, csr_r, csr_w, E);

    // K = 2 propagation steps (second writes straight to output)
    spmm_kernel<<<(N + 3) / 4, 256, 0, stream>>>(h0, h0, dinv, offp, csr_r,
                                                 csr_w, h1, N);
    spmm_kernel<<<(N + 3) / 4, 256, 0, stream>>>(h1, h0, dinv, offp, csr_r,
                                                 csr_w, out_h, N);
}

// Round 6
// 751.339 us; speedup vs baseline: 1.0948x; 1.0948x over previous
//
#include <hip/hip_runtime.h>
#include <hip/hip_bf16.h>

#define IN_DIM 512
#define OUT_DIM 128

typedef short bf16x8 __attribute__((ext_vector_type(8)));   // 8 bf16 (4 VGPRs)
typedef float f32x4  __attribute__((ext_vector_type(4)));   // MFMA acc

static __device__ __forceinline__ unsigned short f32_to_bf16_rne(float f) {
    unsigned u = __builtin_bit_cast(unsigned, f);
    unsigned r = u + 0x7FFFu + ((u >> 16) & 1u);
    return (unsigned short)(r >> 16);
}
static __device__ __forceinline__ float bf16_bits_to_f32(unsigned short h) {
    return __builtin_bit_cast(float, (unsigned)h << 16);
}

// ---------------------------------------------------------------------------
// W[512][128] f32  ->  Th[128][512], Tl[128][512] bf16 bits (transposed split)
// ---------------------------------------------------------------------------
__global__ __launch_bounds__(256) void wtrans_kernel(
    const float* __restrict__ W, short* __restrict__ Th, short* __restrict__ Tl)
{
    const int id = blockIdx.x * 256 + threadIdx.x;   // 65536 total
    const int k = id >> 7;
    const int n = id & 127;
    const float w = W[id];                            // = W[k][n], coalesced
    const unsigned short hb = f32_to_bf16_rne(w);
    const unsigned short lb = f32_to_bf16_rne(w - bf16_bits_to_f32(hb));
    Th[n * 512 + k] = (short)hb;
    Tl[n * 512 + k] = (short)lb;
}

// ---------------------------------------------------------------------------
// Dual split-bf16 MFMA GEMM: C[M][128] = A[M][512] @ W + bias, fp32-accurate
// via A ~ Ah+Al, B ~ Bh+Bl (bf16), C = Ah*Bh + Ah*Bl + Al*Bh (3 MFMA).
// Block: 256 thr (4 waves), tile 128m x 128n, BK=64. Wave tile 64x64
// (4x4 frags of 16x16x32). LDS 64 KB -> 2 blocks/CU.
// XOR swizzle (byte ^= (row&7)<<4) on all LDS tiles: 2-way max conflicts.
// ---------------------------------------------------------------------------
__global__ __launch_bounds__(256) void gemm_dual_kernel(
    const float* __restrict__ A0, const short* __restrict__ Th0,
    const short* __restrict__ Tl0, const float* __restrict__ b0,
    float* __restrict__ C0, int M0, int nb0,
    const float* __restrict__ A1, const short* __restrict__ Th1,
    const short* __restrict__ Tl1, const float* __restrict__ b1,
    float* __restrict__ C1, int M1)
{
    __shared__ short lAh[128 * 64];
    __shared__ short lAl[128 * 64];
    __shared__ short lBh[128 * 64];
    __shared__ short lBl[128 * 64];

    // Block-uniform problem select
    const float* A; const short* Th; const short* Tl; const float* bias;
    float* C; int M, bid;
    if ((int)blockIdx.x < nb0) {
        A = A0; Th = Th0; Tl = Tl0; bias = b0; C = C0; M = M0; bid = blockIdx.x;
    } else {
        A = A1; Th = Th1; Tl = Tl1; bias = b1; C = C1; M = M1;
        bid = blockIdx.x - nb0;
    }

    const int tid  = threadIdx.x;
    const int lane = tid & 63;
    const int wav  = tid >> 6;        // 0..3
    const int wm   = wav >> 1;        // 0..1 (m-half)
    const int wn   = wav & 1;         // 0..1 (n-half)
    const int m0   = bid * 128;

    f32x4 acc[4][4];
#pragma unroll
    for (int i = 0; i < 4; ++i)
#pragma unroll
        for (int j = 0; j < 4; ++j) acc[i][j] = (f32x4){0.f, 0.f, 0.f, 0.f};

    // Staging maps (u = iter*256 + tid over 1024 units of 8 elements)
    const int sr = tid >> 3;          // row base contribution (per iter +32)
    const int sg = tid & 7;           // 8-elem group in row

    // Frag read constants: lane -> (row-in-tile, k-slice)
    const int fr  = lane & 15;        // row/col within 16
    const int fq  = lane >> 4;        // k-group
    const unsigned swz = (unsigned)((lane & 7) << 4);   // (row&7)<<4, row%8==lane%8

    for (int ks = 0; ks < IN_DIM; ks += 64) {
        __syncthreads();
        // ---- stage A: 128x64 f32 -> hi/lo bf16 in LDS ----
#pragma unroll
        for (int it = 0; it < 4; ++it) {
            const int r = it * 32 + sr;           // 0..127
            int grow = m0 + r; if (grow > M - 1) grow = M - 1;
            const float* p = A + (size_t)grow * IN_DIM + ks + sg * 8;
            const float4 fa = *(const float4*)p;
            const float4 fb = *(const float4*)(p + 4);
            const float vals[8] = {fa.x, fa.y, fa.z, fa.w, fb.x, fb.y, fb.z, fb.w};
            bf16x8 h8, l8;
#pragma unroll
            for (int j = 0; j < 8; ++j) {
                const unsigned short hb = f32_to_bf16_rne(vals[j]);
                const unsigned short lb =
                    f32_to_bf16_rne(vals[j] - bf16_bits_to_f32(hb));
                h8[j] = (short)hb; l8[j] = (short)lb;
            }
            const unsigned byte = (unsigned)(r * 128 + sg * 16) ^
                                  (unsigned)((r & 7) << 4);
            *(bf16x8*)((char*)lAh + byte) = h8;
            *(bf16x8*)((char*)lAl + byte) = l8;
        }
        // ---- stage B: pre-split Th/Tl [128n][512k] -> LDS [128n][64k] ----
#pragma unroll
        for (int it = 0; it < 4; ++it) {
            const int n = it * 32 + sr;           // 0..127
            const size_t src = (size_t)n * IN_DIM + ks + sg * 8;
            const bf16x8 h8 = *(const bf16x8*)(Th + src);
            const bf16x8 l8 = *(const bf16x8*)(Tl + src);
            const unsigned byte = (unsigned)(n * 128 + sg * 16) ^
                                  (unsigned)((n & 7) << 4);
            *(bf16x8*)((char*)lBh + byte) = h8;
            *(bf16x8*)((char*)lBl + byte) = l8;
        }
        __syncthreads();

        // ---- MFMA over two k-slices of 32 ----
#pragma unroll
        for (int kk = 0; kk < 2; ++kk) {
            const unsigned cb = (unsigned)(kk * 64 + fq * 16);
            bf16x8 ah[4], al[4], bh[4], bl[4];
#pragma unroll
            for (int mt = 0; mt < 4; ++mt) {
                const int r = wm * 64 + mt * 16 + fr;
                const unsigned byte = ((unsigned)(r * 128) + cb) ^ swz;
                ah[mt] = *(const bf16x8*)((const char*)lAh + byte);
                al[mt] = *(const bf16x8*)((const char*)lAl + byte);
            }
#pragma unroll
            for (int nt = 0; nt < 4; ++nt) {
                const int n = wn * 64 + nt * 16 + fr;
                const unsigned byte = ((unsigned)(n * 128) + cb) ^ swz;
                bh[nt] = *(const bf16x8*)((const char*)lBh + byte);
                bl[nt] = *(const bf16x8*)((const char*)lBl + byte);
            }
#pragma unroll
            for (int mt = 0; mt < 4; ++mt)
#pragma unroll
                for (int nt = 0; nt < 4; ++nt) {
                    acc[mt][nt] = __builtin_amdgcn_mfma_f32_16x16x32_bf16(
                        ah[mt], bh[nt], acc[mt][nt], 0, 0, 0);
                    acc[mt][nt] = __builtin_amdgcn_mfma_f32_16x16x32_bf16(
                        ah[mt], bl[nt], acc[mt][nt], 0, 0, 0);
                    acc[mt][nt] = __builtin_amdgcn_mfma_f32_16x16x32_bf16(
                        al[mt], bh[nt], acc[mt][nt], 0, 0, 0);
                }
        }
    }

    // ---- epilogue: bias + store. C/D layout: col=lane&15, row=(lane>>4)*4+i
    float bv[4];
#pragma unroll
    for (int nt = 0; nt < 4; ++nt) bv[nt] = bias[wn * 64 + nt * 16 + fr];
#pragma unroll
    for (int mt = 0; mt < 4; ++mt) {
#pragma unroll
        for (int i = 0; i < 4; ++i) {
            const int row = m0 + wm * 64 + mt * 16 + fq * 4 + i;
            if (row < M) {
                float* cp = C + (size_t)row * OUT_DIM + wn * 64 + fr;
#pragma unroll
                for (int nt = 0; nt < 4; ++nt)
                    cp[nt * 16] = acc[mt][nt][i] + bv[nt];
            }
        }
    }
}

// ---------------------------------------------------------------------------
// In-degree count over target nodes (self-loop added analytically later)
// ---------------------------------------------------------------------------
__global__ void count_kernel(const int* __restrict__ col, int* __restrict__ cnt,
                             int E)
{
    for (int e = blockIdx.x * blockDim.x + threadIdx.x; e < E;
         e += gridDim.x * blockDim.x)
        atomicAdd(&cnt[col[e]], 1);
}

__global__ void dinv_kernel(const int* __restrict__ cnt,
                            float* __restrict__ dinv, int N)
{
    int n = blockIdx.x * blockDim.x + threadIdx.x;
    if (n < N) dinv[n] = rsqrtf((float)cnt[n] + 1.0f);  // deg = cnt + self loop
}

// ---------------------------------------------------------------------------
// Thread-coarsened single-block exclusive scan (~20 barriers total)
// ---------------------------------------------------------------------------
__global__ __launch_bounds__(1024) void scan_kernel(
    const int* __restrict__ cnt, int* __restrict__ off, int* __restrict__ cur,
    int N)
{
    __shared__ int buf[1024];
    const int tid   = threadIdx.x;
    const int chunk = (N + 1023) / 1024;
    const int lo    = tid * chunk;
    const int hi    = min(N, lo + chunk);

    int total = 0;
    for (int i = lo; i < hi; ++i) total += cnt[i];
    buf[tid] = total;
    __syncthreads();
#pragma unroll
    for (int ofs = 1; ofs < 1024; ofs <<= 1) {
        const int t = (tid >= ofs) ? buf[tid - ofs] : 0;
        __syncthreads();
        buf[tid] += t;
        __syncthreads();
    }
    int running = buf[tid] - total;
    for (int i = lo; i < hi; ++i) {
        off[i] = running;
        cur[i] = running;
        running += cnt[i];
    }
    if (tid == 1023) off[N] = running;
}

// ---------------------------------------------------------------------------
// CSR fill: bucket edges by target; store source index + dinv[source]
// ---------------------------------------------------------------------------
__global__ void fill_kernel(const int* __restrict__ row,
                            const int* __restrict__ col,
                            const float* __restrict__ dinv,
                            int* __restrict__ cur, int* __restrict__ csr_row,
                            float* __restrict__ csr_w, int E)
{
    for (int e = blockIdx.x * blockDim.x + threadIdx.x; e < E;
         e += gridDim.x * blockDim.x) {
        const int c = col[e];
        const int r = row[e];
        const int p = atomicAdd(&cur[c], 1);
        csr_row[p] = r;
        csr_w[p]   = dinv[r];
    }
}

// ---------------------------------------------------------------------------
// Gather-form SpMM + APPNP update; one wave per node, lane = 2 features.
// 8-way edge unroll for memory-level parallelism on the L3-random gathers.
// ---------------------------------------------------------------------------
__global__ __launch_bounds__(256) void spmm_kernel(
    const float* __restrict__ hin, const float* __restrict__ h0,
    const float* __restrict__ dinv, const int* __restrict__ off,
    const int* __restrict__ csr_row, const float* __restrict__ csr_w,
    float* __restrict__ hout, int N)
{
    const int wave = threadIdx.x >> 6;
    const int lane = threadIdx.x & 63;
    const int n = blockIdx.x * 4 + wave;
    if (n >= N) return;
    const int f = lane * 2;

    float acc0 = 0.0f, acc1 = 0.0f;
    const int s = off[n];
    const int e = off[n + 1];

    int i = s;
    for (; i + 7 < e; i += 8) {
        int   rr[8]; float ww[8]; float2 vv[8];
#pragma unroll
        for (int j = 0; j < 8; ++j) { rr[j] = csr_row[i + j]; ww[j] = csr_w[i + j]; }
#pragma unroll
        for (int j = 0; j < 8; ++j)
            vv[j] = *(const float2*)(hin + (size_t)rr[j] * OUT_DIM + f);
#pragma unroll
        for (int j = 0; j < 8; ++j) {
            acc0 = fmaf(ww[j], vv[j].x, acc0);
            acc1 = fmaf(ww[j], vv[j].y, acc1);
        }
    }
    for (; i < e; ++i) {
        const int   r = csr_row[i];
        const float w = csr_w[i];
        const float2 v = *(const float2*)(hin + (size_t)r * OUT_DIM + f);
        acc0 = fmaf(w, v.x, acc0);
        acc1 = fmaf(w, v.y, acc1);
    }

    const float di  = dinv[n];
    const float2 hs  = *(const float2*)(hin + (size_t)n * OUT_DIM + f);
    const float2 h0v = *(const float2*)(h0  + (size_t)n * OUT_DIM + f);
    float2 o;
    o.x = 0.9f * (di * acc0 + di * di * hs.x) + 0.1f * h0v.x;
    o.y = 0.9f * (di * acc1 + di * di * hs.y) + 0.1f * h0v.y;
    *(float2*)(hout + (size_t)n * OUT_DIM + f) = o;
}

// ---------------------------------------------------------------------------
extern "C" void kernel_launch(void* const* d_in, const int* in_sizes, int n_in,
                              void* d_out, int out_size, void* d_ws,
                              size_t ws_size, hipStream_t stream)
{
    const float* x     = (const float*)d_in[0];
    const int*   ei    = (const int*)d_in[1];
    const float* q_emb = (const float*)d_in[2];
    const float* W_t   = (const float*)d_in[3];
    const float* b_t   = (const float*)d_in[4];
    const float* W_q   = (const float*)d_in[5];
    const float* b_q   = (const float*)d_in[6];

    const int OUT = in_sizes[4];            // 128
    const int IN  = in_sizes[3] / OUT;      // 512
    const int N   = in_sizes[0] / IN;       // 50000
    const int E   = in_sizes[1] / 2;        // 800000
    const int NQ  = in_sizes[2] / IN;       // 100000

    const int* row = ei;                    // edge_index[0] (source)
    const int* col = ei + E;                // edge_index[1] (target)

    // Workspace layout (256B-aligned slices)
    char*  w   = (char*)d_ws;
    size_t ofs = 0;
    auto take = [&](size_t bytes) -> void* {
        void* p = w + ofs;
        ofs += (bytes + 255) & ~(size_t)255;
        return p;
    };
    float* h0    = (float*)take((size_t)N * OUT * 4);
    float* h1    = (float*)take((size_t)N * OUT * 4);
    float* dinv  = (float*)take((size_t)N * 4);
    int*   cnt   = (int*)take((size_t)N * 4);
    int*   offp  = (int*)take((size_t)(N + 1) * 4);
    int*   cur   = (int*)take((size_t)N * 4);
    int*   csr_r = (int*)take((size_t)E * 4);
    float* csr_w = (float*)take((size_t)E * 4);
    short* Tq_h  = (short*)take((size_t)IN * OUT * 2);   // W_q^T hi
    short* Tq_l  = (short*)take((size_t)IN * OUT * 2);   // W_q^T lo
    short* Tt_h  = (short*)take((size_t)IN * OUT * 2);   // W_t^T hi
    short* Tt_l  = (short*)take((size_t)IN * OUT * 2);   // W_t^T lo
    (void)ws_size; (void)n_in; (void)out_size;

    float* out_q = (float*)d_out;                       // [NQ, OUT]
    float* out_h = (float*)d_out + (size_t)NQ * OUT;    // [N, OUT]

    hipMemsetAsync(cnt, 0, (size_t)N * 4, stream);

    // Weight transpose + bf16 hi/lo split (one-shot, ~65k threads each)
    wtrans_kernel<<<256, 256, 0, stream>>>(W_q, Tq_h, Tq_l);
    wtrans_kernel<<<256, 256, 0, stream>>>(W_t, Tt_h, Tt_l);

    // Dense encoders — single fused MFMA dispatch
    const int nb_q = (NQ + 127) / 128;      // 782
    const int nb_t = (N + 127) / 128;       // 391
    gemm_dual_kernel<<<nb_q + nb_t, 256, 0, stream>>>(
        q_emb, Tq_h, Tq_l, b_q, out_q, NQ, nb_q,
        x,     Tt_h, Tt_l, b_t, h0,    N);

    // Graph preprocessing: degree -> dinv -> CSR by target
    count_kernel<<<1024, 256, 0, stream>>>(col, cnt, E);
    dinv_kernel<<<(N + 255) / 256, 256, 0, stream>>>(cnt, dinv, N);
    scan_kernel<<<1, 1024, 0, stream>>>(cnt, offp, cur, N);
    fill_kernel<<<1024, 256, 0, stream>>>(row, col, dinv, cur, csr_r, csr_w, E);

    // K = 2 propagation steps (second writes straight to output)
    spmm_kernel<<<(N + 3) / 4, 256, 0, stream>>>(h0, h0, dinv, offp, csr_r,
                                                 csr_w, h1, N);
    spmm_kernel<<<(N + 3) / 4, 256, 0, stream>>>(h1, h0, dinv, offp, csr_r,
                                                 csr_w, out_h, N);
}